// Round 1
// baseline (575.543 us; speedup 1.0000x reference)
//
#include <hip/hip_runtime.h>
#include <math.h>

#define H2 128

// ---------------- init: deg=1 (self loop), cursor=0, pool=0, total=0 ----------------
__global__ __launch_bounds__(256) void k_init(int* __restrict__ deg, int* __restrict__ cursor,
                                              float* __restrict__ pool, int* __restrict__ total, int N) {
  int i = blockIdx.x * 256 + threadIdx.x;
  if (i < N) { deg[i] = 1; cursor[i] = 0; }
  if (i < H2) pool[i] = 0.f;
  if (i == 0) *total = 0;
}

// ---------------- in-degree histogram (counts edges by destination) ----------------
__global__ __launch_bounds__(256) void k_degree(const int* __restrict__ col, int* __restrict__ deg, int E) {
  int e = blockIdx.x * 256 + threadIdx.x;
  if (e < E) atomicAdd(&deg[col[e]], 1);
}

// ---------------- dis = rsqrt(deg); col_off via atomic running offset ----------------
// (segment placement order is non-deterministic but each node owns a private
//  contiguous range of size deg-1; only fp summation order varies -> ~1e-6 jitter)
__global__ __launch_bounds__(256) void k_offs(const int* __restrict__ deg, float* __restrict__ dis,
                                              int* __restrict__ col_off, int* __restrict__ total, int N) {
  int i = blockIdx.x * 256 + threadIdx.x;
  if (i < N) {
    int d = deg[i];
    dis[i] = rsqrtf((float)d);
    col_off[i] = atomicAdd(total, d - 1);
  }
}

// ---------------- scatter edges into CSR-by-destination ----------------
__global__ __launch_bounds__(256) void k_scatter(const int* __restrict__ row, const int* __restrict__ col,
                                                 const int* __restrict__ col_off, int* __restrict__ cursor,
                                                 int* __restrict__ csr_src, int E) {
  int e = blockIdx.x * 256 + threadIdx.x;
  if (e < E) {
    int c = col[e];
    int p = col_off[c] + atomicAdd(&cursor[c], 1);
    csr_src[p] = row[e];
  }
}

// ---------------- layer-1 aggregation of raw x (4 dims per node) ----------------
// aggx[c] = dis[c] * sum_{r->c} dis[r]*x[r]  +  dis[c]^2 * x[c]
__global__ __launch_bounds__(256) void k_l1gather(const float* __restrict__ x, const int* __restrict__ csr_src,
                                                  const int* __restrict__ col_off, const int* __restrict__ deg,
                                                  const float* __restrict__ dis, float* __restrict__ aggx, int N) {
  int c = blockIdx.x * 256 + threadIdx.x;
  if (c >= N) return;
  float dc = dis[c];
  int base = col_off[c];
  int cnt = deg[c] - 1;
  float4 xs = ((const float4*)x)[c];
  float ax = 0.f, ay = 0.f, az = 0.f, aw = 0.f;
  for (int j = 0; j < cnt; ++j) {
    int r = csr_src[base + j];
    float w = dis[r];
    float4 xr = ((const float4*)x)[r];
    ax = fmaf(w, xr.x, ax);
    ay = fmaf(w, xr.y, ay);
    az = fmaf(w, xr.z, az);
    aw = fmaf(w, xr.w, aw);
  }
  float d2 = dc * dc;
  float4 o;
  o.x = fmaf(dc, ax, d2 * xs.x);
  o.y = fmaf(dc, ay, d2 * xs.y);
  o.z = fmaf(dc, az, d2 * xs.z);
  o.w = fmaf(dc, aw, d2 * xs.w);
  ((float4*)aggx)[c] = o;
}

// ---------------- fused: h1 = relu(aggx@W1 + b1) computed in LDS, t2 = h1@W2 ----------------
// Block tile: 64 nodes x 128 cols (full width). K-loop over 256 in chunks of 32.
__global__ __launch_bounds__(256) void k_gemm(const float* __restrict__ aggx, const float* __restrict__ W1,
                                              const float* __restrict__ b1, const float* __restrict__ W2,
                                              float* __restrict__ t2, int N) {
  __shared__ float ax[64][4];
  __shared__ float h1s[64][33];                 // +1 pad
  __shared__ __align__(16) float w2s[32][128];
  int tid = threadIdx.x;
  int node0 = blockIdx.x * 64;
  {
    int n = tid >> 2, k = tid & 3;
    int node = node0 + n;
    ax[n][k] = (node < N) ? aggx[node * 4 + k] : 0.f;
  }
  __syncthreads();
  float acc[8][4];
#pragma unroll
  for (int r = 0; r < 8; ++r)
#pragma unroll
    for (int cc = 0; cc < 4; ++cc) acc[r][cc] = 0.f;
  int tx = tid & 31, ty = tid >> 5;
  for (int it = 0; it < 8; ++it) {
    // compute 64x32 h1 chunk (8 values per thread)
#pragma unroll
    for (int q = 0; q < 8; ++q) {
      int lin = tid + 256 * q;
      int n = lin >> 5, kk = lin & 31;
      int j = it * 32 + kk;
      float v = b1[j];
      v = fmaf(ax[n][0], W1[j], v);
      v = fmaf(ax[n][1], W1[256 + j], v);
      v = fmaf(ax[n][2], W1[512 + j], v);
      v = fmaf(ax[n][3], W1[768 + j], v);
      h1s[n][kk] = fmaxf(v, 0.f);
    }
    // stage 32x128 W2 chunk (16 values per thread, coalesced)
#pragma unroll
    for (int q = 0; q < 16; ++q) {
      int lin = tid + 256 * q;
      int kk = lin >> 7, cc = lin & 127;
      w2s[kk][cc] = W2[(it * 32 + kk) * 128 + cc];
    }
    __syncthreads();
#pragma unroll
    for (int kk = 0; kk < 32; ++kk) {
      float4 bv = *(const float4*)&w2s[kk][tx * 4];
#pragma unroll
      for (int r = 0; r < 8; ++r) {
        float a = h1s[ty * 8 + r][kk];
        acc[r][0] = fmaf(a, bv.x, acc[r][0]);
        acc[r][1] = fmaf(a, bv.y, acc[r][1]);
        acc[r][2] = fmaf(a, bv.z, acc[r][2]);
        acc[r][3] = fmaf(a, bv.w, acc[r][3]);
      }
    }
    __syncthreads();
  }
#pragma unroll
  for (int r = 0; r < 8; ++r) {
    int node = node0 + ty * 8 + r;
    if (node < N) {
      float4 o = make_float4(acc[r][0], acc[r][1], acc[r][2], acc[r][3]);
      *(float4*)&t2[(size_t)node * 128 + tx * 4] = o;
    }
  }
}

// ---------------- layer-2 aggregation + relu + mean-pool accumulation ----------------
// One wave per node (grid-stride). Lane l covers dims 2l, 2l+1 (float2 -> one 512B
// coalesced read per source row). Pool partials in registers, block-reduce, atomic.
__global__ __launch_bounds__(256) void k_agg2(const int* __restrict__ csr_src, const int* __restrict__ col_off,
                                              const int* __restrict__ deg, const float* __restrict__ dis,
                                              const float* __restrict__ t2, const float* __restrict__ b2,
                                              float* __restrict__ pool, int N) {
  int wave = threadIdx.x >> 6;
  int lane = threadIdx.x & 63;
  int gw = blockIdx.x * 4 + wave;
  int nw = gridDim.x * 4;
  float2 bb = *(const float2*)&b2[lane * 2];
  float p0 = 0.f, p1 = 0.f;
  for (int c = gw; c < N; c += nw) {
    float dc = dis[c];
    int base = col_off[c];
    int cnt = deg[c] - 1;
    float2 sl = *(const float2*)&t2[(size_t)c * 128 + lane * 2];
    float d2 = dc * dc;
    float a0 = d2 * sl.x, a1 = d2 * sl.y;
    for (int j = 0; j < cnt; ++j) {
      int r = csr_src[base + j];           // same addr across wave -> broadcast
      float w = dc * dis[r];
      float2 v = *(const float2*)&t2[(size_t)r * 128 + lane * 2];
      a0 = fmaf(w, v.x, a0);
      a1 = fmaf(w, v.y, a1);
    }
    p0 += fmaxf(a0 + bb.x, 0.f);
    p1 += fmaxf(a1 + bb.y, 0.f);
  }
  __shared__ float red[4][128];
  red[wave][lane * 2] = p0;
  red[wave][lane * 2 + 1] = p1;
  __syncthreads();
  if (threadIdx.x < 128) {
    float s = red[0][threadIdx.x] + red[1][threadIdx.x] + red[2][threadIdx.x] + red[3][threadIdx.x];
    atomicAdd(&pool[threadIdx.x], s);
  }
}

// ---------------- final: g = pool/N; out = sigmoid(g@Wl + bl) ----------------
__global__ __launch_bounds__(128) void k_final(const float* __restrict__ pool, const float* __restrict__ Wl,
                                               const float* __restrict__ bl, float* __restrict__ out, float invN) {
  __shared__ float red[128];
  int t = threadIdx.x;
  red[t] = pool[t] * invN * Wl[t];
  __syncthreads();
  for (int s = 64; s > 0; s >>= 1) {
    if (t < s) red[t] += red[t + s];
    __syncthreads();
  }
  if (t == 0) out[0] = 1.f / (1.f + expf(-(red[0] + bl[0])));
}

extern "C" void kernel_launch(void* const* d_in, const int* in_sizes, int n_in,
                              void* d_out, int out_size, void* d_ws, size_t ws_size,
                              hipStream_t stream) {
  const float* x  = (const float*)d_in[0];
  const int*   ei = (const int*)d_in[1];   // int32 per harness convention (jax default x64 off)
  const float* W1 = (const float*)d_in[2];
  const float* b1 = (const float*)d_in[3];
  const float* W2 = (const float*)d_in[4];
  const float* b2 = (const float*)d_in[5];
  const float* Wl = (const float*)d_in[6];
  const float* bl = (const float*)d_in[7];
  int N = in_sizes[0] / 4;
  int E = in_sizes[1] / 2;
  const int* row = ei;       // sources
  const int* col = ei + E;   // destinations

  char* w = (char*)d_ws;
  size_t off = 0;
  auto alloc = [&](size_t bytes) {
    void* p = w + off;
    off += (bytes + 255) & ~(size_t)255;
    return p;
  };
  int*   deg     = (int*)alloc((size_t)N * 4);
  float* dis     = (float*)alloc((size_t)N * 4);
  int*   col_off = (int*)alloc((size_t)N * 4);
  int*   cursor  = (int*)alloc((size_t)N * 4);
  int*   csr_src = (int*)alloc((size_t)E * 4);
  float* aggx    = (float*)alloc((size_t)N * 16);
  float* t2      = (float*)alloc((size_t)N * H2 * 4);
  float* pool    = (float*)alloc(H2 * 4);
  int*   total   = (int*)alloc(4);
  (void)ws_size; (void)n_in; (void)out_size;

  int gN = (N + 255) / 256;
  int gE = (E + 255) / 256;

  k_init<<<gN, 256, 0, stream>>>(deg, cursor, pool, total, N);
  k_degree<<<gE, 256, 0, stream>>>(col, deg, E);
  k_offs<<<gN, 256, 0, stream>>>(deg, dis, col_off, total, N);
  k_scatter<<<gE, 256, 0, stream>>>(row, col, col_off, cursor, csr_src, E);
  k_l1gather<<<gN, 256, 0, stream>>>(x, csr_src, col_off, deg, dis, aggx, N);
  k_gemm<<<(N + 63) / 64, 256, 0, stream>>>(aggx, W1, b1, W2, t2, N);
  k_agg2<<<2048, 256, 0, stream>>>(csr_src, col_off, deg, dis, t2, b2, pool, N);
  k_final<<<1, 128, 0, stream>>>(pool, Wl, bl, (float*)d_out, 1.0f / (float)N);
}

// Round 2
// 556.830 us; speedup vs baseline: 1.0336x; 1.0336x over previous
//
#include <hip/hip_runtime.h>
#include <math.h>

#define H2 128

typedef unsigned short ushort_t;
typedef unsigned int uint_t;

static __device__ inline uint_t pack_bf16x2(float a, float b) {
  uint_t ua = __float_as_uint(a); ua += 0x7fffu + ((ua >> 16) & 1u);
  uint_t ub = __float_as_uint(b); ub += 0x7fffu + ((ub >> 16) & 1u);
  return (ua >> 16) | (ub & 0xffff0000u);
}

// ---------------- init: deg=1 (self loop), cursor=0, pool=0, total=0 ----------------
__global__ __launch_bounds__(256) void k_init(int* __restrict__ deg, int* __restrict__ cursor,
                                              float* __restrict__ pool, int* __restrict__ total, int N) {
  int i = blockIdx.x * 256 + threadIdx.x;
  if (i < N) { deg[i] = 1; cursor[i] = 0; }
  if (i < H2) pool[i] = 0.f;
  if (i == 0) *total = 0;
}

// ---------------- in-degree histogram (counts edges by destination) ----------------
__global__ __launch_bounds__(256) void k_degree(const int* __restrict__ col, int* __restrict__ deg, int E) {
  int e = blockIdx.x * 256 + threadIdx.x;
  if (e < E) atomicAdd(&deg[col[e]], 1);
}

// ---------------- dis = rsqrt(deg); col_off via wave-prefix + 1 atomic/wave ----------------
// (avoids 100K serialized same-address atomics; placement order still gives each node a
//  private contiguous range, only fp summation order varies)
__global__ __launch_bounds__(256) void k_offs(const int* __restrict__ deg, float* __restrict__ dis,
                                              int* __restrict__ col_off, int* __restrict__ total, int N) {
  int i = blockIdx.x * 256 + threadIdx.x;
  int lane = threadIdx.x & 63;
  int d = (i < N) ? deg[i] : 1;          // v=0 for OOB lanes
  if (i < N) dis[i] = rsqrtf((float)d);
  int v = d - 1;
  int pref = v;                           // inclusive wave prefix sum
#pragma unroll
  for (int s = 1; s < 64; s <<= 1) {
    int t = __shfl_up(pref, s, 64);
    if (lane >= s) pref += t;
  }
  int wavesum = __shfl(pref, 63, 64);
  int base = 0;
  if (lane == 63) base = atomicAdd(total, wavesum);
  base = __shfl(base, 63, 64);
  if (i < N) col_off[i] = base + pref - v;  // exclusive prefix within wave
}

// ---------------- scatter edges into CSR-by-destination ----------------
__global__ __launch_bounds__(256) void k_scatter(const int* __restrict__ row, const int* __restrict__ col,
                                                 const int* __restrict__ col_off, int* __restrict__ cursor,
                                                 int* __restrict__ csr_src, int E) {
  int e = blockIdx.x * 256 + threadIdx.x;
  if (e < E) {
    int c = col[e];
    int p = col_off[c] + atomicAdd(&cursor[c], 1);
    csr_src[p] = row[e];
  }
}

// ---------------- layer-1 aggregation of raw x (4 dims per node) ----------------
__global__ __launch_bounds__(256) void k_l1gather(const float* __restrict__ x, const int* __restrict__ csr_src,
                                                  const int* __restrict__ col_off, const int* __restrict__ deg,
                                                  const float* __restrict__ dis, float* __restrict__ aggx, int N) {
  int c = blockIdx.x * 256 + threadIdx.x;
  if (c >= N) return;
  float dc = dis[c];
  int base = col_off[c];
  int cnt = deg[c] - 1;
  float4 xs = ((const float4*)x)[c];
  float ax = 0.f, ay = 0.f, az = 0.f, aw = 0.f;
  for (int j = 0; j < cnt; ++j) {
    int r = csr_src[base + j];
    float w = dis[r];
    float4 xr = ((const float4*)x)[r];
    ax = fmaf(w, xr.x, ax);
    ay = fmaf(w, xr.y, ay);
    az = fmaf(w, xr.z, az);
    aw = fmaf(w, xr.w, aw);
  }
  float d2 = dc * dc;
  float4 o;
  o.x = fmaf(dc, ax, d2 * xs.x);
  o.y = fmaf(dc, ay, d2 * xs.y);
  o.z = fmaf(dc, az, d2 * xs.z);
  o.w = fmaf(dc, aw, d2 * xs.w);
  ((float4*)aggx)[c] = o;
}

// ---------------- fused: h1 = relu(aggx@W1 + b1) in LDS, t2 = h1@W2 (bf16 out) ----------------
__global__ __launch_bounds__(256) void k_gemm(const float* __restrict__ aggx, const float* __restrict__ W1,
                                              const float* __restrict__ b1, const float* __restrict__ W2,
                                              ushort_t* __restrict__ t2, int N) {
  __shared__ float ax[64][4];
  __shared__ float h1s[64][33];                 // +1 pad
  __shared__ __align__(16) float w2s[32][128];
  int tid = threadIdx.x;
  int node0 = blockIdx.x * 64;
  {
    int n = tid >> 2, k = tid & 3;
    int node = node0 + n;
    ax[n][k] = (node < N) ? aggx[node * 4 + k] : 0.f;
  }
  __syncthreads();
  float acc[8][4];
#pragma unroll
  for (int r = 0; r < 8; ++r)
#pragma unroll
    for (int cc = 0; cc < 4; ++cc) acc[r][cc] = 0.f;
  int tx = tid & 31, ty = tid >> 5;
  for (int it = 0; it < 8; ++it) {
#pragma unroll
    for (int q = 0; q < 8; ++q) {
      int lin = tid + 256 * q;
      int n = lin >> 5, kk = lin & 31;
      int j = it * 32 + kk;
      float v = b1[j];
      v = fmaf(ax[n][0], W1[j], v);
      v = fmaf(ax[n][1], W1[256 + j], v);
      v = fmaf(ax[n][2], W1[512 + j], v);
      v = fmaf(ax[n][3], W1[768 + j], v);
      h1s[n][kk] = fmaxf(v, 0.f);
    }
#pragma unroll
    for (int q = 0; q < 16; ++q) {
      int lin = tid + 256 * q;
      int kk = lin >> 7, cc = lin & 127;
      w2s[kk][cc] = W2[(it * 32 + kk) * 128 + cc];
    }
    __syncthreads();
#pragma unroll
    for (int kk = 0; kk < 32; ++kk) {
      float4 bv = *(const float4*)&w2s[kk][tx * 4];
#pragma unroll
      for (int r = 0; r < 8; ++r) {
        float a = h1s[ty * 8 + r][kk];
        acc[r][0] = fmaf(a, bv.x, acc[r][0]);
        acc[r][1] = fmaf(a, bv.y, acc[r][1]);
        acc[r][2] = fmaf(a, bv.z, acc[r][2]);
        acc[r][3] = fmaf(a, bv.w, acc[r][3]);
      }
    }
    __syncthreads();
  }
#pragma unroll
  for (int r = 0; r < 8; ++r) {
    int node = node0 + ty * 8 + r;
    if (node < N) {
      uint_t p0 = pack_bf16x2(acc[r][0], acc[r][1]);
      uint_t p1 = pack_bf16x2(acc[r][2], acc[r][3]);
      uint2 o = make_uint2(p0, p1);
      *(uint2*)(t2 + (size_t)node * 128 + tx * 4) = o;
    }
  }
}

// ---------------- layer-2 aggregation (bf16 t2) + relu + mean-pool ----------------
// One wave per node. Lane l reads one packed bf16x2 dword (dims 2l,2l+1):
// 64 lanes x 4 B = one 256 B coalesced read per source row.
__global__ __launch_bounds__(256) void k_agg2(const int* __restrict__ csr_src, const int* __restrict__ col_off,
                                              const int* __restrict__ deg, const float* __restrict__ dis,
                                              const ushort_t* __restrict__ t2, const float* __restrict__ b2,
                                              float* __restrict__ pool, int N) {
  int wave = threadIdx.x >> 6;
  int lane = threadIdx.x & 63;
  int gw = blockIdx.x * 4 + wave;
  int nw = gridDim.x * 4;
  float2 bb = *(const float2*)&b2[lane * 2];
  float p0 = 0.f, p1 = 0.f;
  for (int c = gw; c < N; c += nw) {
    float dc = dis[c];
    int base = col_off[c];
    int cnt = deg[c] - 1;
    uint_t us = *(const uint_t*)(t2 + (size_t)c * 128 + lane * 2);
    float d2 = dc * dc;
    float a0 = d2 * __uint_as_float(us << 16);
    float a1 = d2 * __uint_as_float(us & 0xffff0000u);
    for (int j = 0; j < cnt; ++j) {
      int r = csr_src[base + j];           // same addr across wave -> broadcast
      float w = dc * dis[r];
      uint_t u = *(const uint_t*)(t2 + (size_t)r * 128 + lane * 2);
      a0 = fmaf(w, __uint_as_float(u << 16), a0);
      a1 = fmaf(w, __uint_as_float(u & 0xffff0000u), a1);
    }
    p0 += fmaxf(a0 + bb.x, 0.f);
    p1 += fmaxf(a1 + bb.y, 0.f);
  }
  __shared__ float red[4][128];
  red[wave][lane * 2] = p0;
  red[wave][lane * 2 + 1] = p1;
  __syncthreads();
  if (threadIdx.x < 128) {
    float s = red[0][threadIdx.x] + red[1][threadIdx.x] + red[2][threadIdx.x] + red[3][threadIdx.x];
    atomicAdd(&pool[threadIdx.x], s);
  }
}

// ---------------- final: g = pool/N; out = sigmoid(g@Wl + bl) ----------------
__global__ __launch_bounds__(128) void k_final(const float* __restrict__ pool, const float* __restrict__ Wl,
                                               const float* __restrict__ bl, float* __restrict__ out, float invN) {
  __shared__ float red[128];
  int t = threadIdx.x;
  red[t] = pool[t] * invN * Wl[t];
  __syncthreads();
  for (int s = 64; s > 0; s >>= 1) {
    if (t < s) red[t] += red[t + s];
    __syncthreads();
  }
  if (t == 0) out[0] = 1.f / (1.f + expf(-(red[0] + bl[0])));
}

extern "C" void kernel_launch(void* const* d_in, const int* in_sizes, int n_in,
                              void* d_out, int out_size, void* d_ws, size_t ws_size,
                              hipStream_t stream) {
  const float* x  = (const float*)d_in[0];
  const int*   ei = (const int*)d_in[1];
  const float* W1 = (const float*)d_in[2];
  const float* b1 = (const float*)d_in[3];
  const float* W2 = (const float*)d_in[4];
  const float* b2 = (const float*)d_in[5];
  const float* Wl = (const float*)d_in[6];
  const float* bl = (const float*)d_in[7];
  int N = in_sizes[0] / 4;
  int E = in_sizes[1] / 2;
  const int* row = ei;       // sources
  const int* col = ei + E;   // destinations

  char* w = (char*)d_ws;
  size_t off = 0;
  auto alloc = [&](size_t bytes) {
    void* p = w + off;
    off += (bytes + 255) & ~(size_t)255;
    return p;
  };
  int*      deg     = (int*)alloc((size_t)N * 4);
  float*    dis     = (float*)alloc((size_t)N * 4);
  int*      col_off = (int*)alloc((size_t)N * 4);
  int*      cursor  = (int*)alloc((size_t)N * 4);
  int*      csr_src = (int*)alloc((size_t)E * 4);
  float*    aggx    = (float*)alloc((size_t)N * 16);
  ushort_t* t2      = (ushort_t*)alloc((size_t)N * H2 * 2);
  float*    pool    = (float*)alloc(H2 * 4);
  int*      total   = (int*)alloc(4);
  (void)ws_size; (void)n_in; (void)out_size;

  int gN = (N + 255) / 256;
  int gE = (E + 255) / 256;

  k_init<<<gN, 256, 0, stream>>>(deg, cursor, pool, total, N);
  k_degree<<<gE, 256, 0, stream>>>(col, deg, E);
  k_offs<<<gN, 256, 0, stream>>>(deg, dis, col_off, total, N);
  k_scatter<<<gE, 256, 0, stream>>>(row, col, col_off, cursor, csr_src, E);
  k_l1gather<<<gN, 256, 0, stream>>>(x, csr_src, col_off, deg, dis, aggx, N);
  k_gemm<<<(N + 63) / 64, 256, 0, stream>>>(aggx, W1, b1, W2, t2, N);
  k_agg2<<<2048, 256, 0, stream>>>(csr_src, col_off, deg, dis, t2, b2, pool, N);
  k_final<<<1, 128, 0, stream>>>(pool, Wl, bl, (float*)d_out, 1.0f / (float)N);
}